// Round 5
// baseline (71.279 us; speedup 1.0000x reference)
//
#include <hip/hip_runtime.h>

#define NPRE 32768
#define NPOST 32768
#define RR 64
#define BATCH 512
#define KSPLIT 128
#define KCHUNK 256  // NPRE / KSPLIT

typedef float f32x4 __attribute__((ext_vector_type(4)));
typedef __bf16 bf16x8 __attribute__((ext_vector_type(8)));
typedef unsigned short u16;
typedef unsigned int u32;

static __device__ __forceinline__ u16 f2bfu(float f) {
  u32 u = __builtin_bit_cast(u32, f);
  return (u16)((u + 0x7fffu + ((u >> 16) & 1u)) >> 16);  // RNE round to bf16
}
static __device__ __forceinline__ __bf16 u2bf(u16 s) {
  return __builtin_bit_cast(__bf16, s);
}
static __device__ __forceinline__ float bf2f(u16 s) {
  return __builtin_bit_cast(float, (u32)s << 16);
}
static __device__ __forceinline__ bf16x8 cvt8(f32x4 lo, f32x4 hi) {
  bf16x8 b;
  b[0] = u2bf(f2bfu(lo.x)); b[1] = u2bf(f2bfu(lo.y));
  b[2] = u2bf(f2bfu(lo.z)); b[3] = u2bf(f2bfu(lo.w));
  b[4] = u2bf(f2bfu(hi.x)); b[5] = u2bf(f2bfu(hi.y));
  b[6] = u2bf(f2bfu(hi.z)); b[7] = u2bf(f2bfu(hi.w));
  return b;
}

// ---- GEMM1: zp[kc][b][r] = S[b][kslice] @ V[kslice][r], bf16 partials -----
// (unchanged — frozen for attribution this round)
__global__ __launch_bounds__(256, 4) void k1(const float* __restrict__ S,
                                             const float* __restrict__ V,
                                             u16* __restrict__ zp) {
  int bid = blockIdx.x;
  int eff = (bid & 7) * 128 + (bid >> 3);  // bijective XCD swizzle (1024 % 8 == 0)
  int grp = eff & 7;
  int kc = eff >> 3;                       // XCD-contiguous kc range
  int lane = threadIdx.x & 63;
  int w = threadIdx.x >> 6;
  int mt = grp * 4 + w;                    // 0..31
  int l15 = lane & 15, g = lane >> 4;
  const float* A = S + (size_t)(mt * 16 + l15) * NPRE + kc * KCHUNK + g * 8;
  const float* Vb = V + (size_t)(kc * KCHUNK + g * 8) * RR + l15;
  f32x4 acc[4] = {};
#pragma unroll 2
  for (int ks = 0; ks < KCHUNK / 32; ++ks) {
    f32x4 a0 = __builtin_nontemporal_load(reinterpret_cast<const f32x4*>(A + ks * 32));
    f32x4 a1 = __builtin_nontemporal_load(reinterpret_cast<const f32x4*>(A + ks * 32 + 4));
    bf16x8 af = cvt8(a0, a1);
    const float* Vk = Vb + (size_t)ks * 32 * RR;
    bf16x8 bfr[4];
#pragma unroll
    for (int t = 0; t < 4; ++t)
#pragma unroll
      for (int j = 0; j < 8; ++j)
        bfr[t][j] = u2bf(f2bfu(Vk[j * RR + t * 16]));  // V[k][r], r = t*16+l15
    acc[0] = __builtin_amdgcn_mfma_f32_16x16x32_bf16(af, bfr[0], acc[0], 0, 0, 0);
    acc[1] = __builtin_amdgcn_mfma_f32_16x16x32_bf16(af, bfr[1], acc[1], 0, 0, 0);
    acc[2] = __builtin_amdgcn_mfma_f32_16x16x32_bf16(af, bfr[2], acc[2], 0, 0, 0);
    acc[3] = __builtin_amdgcn_mfma_f32_16x16x32_bf16(af, bfr[3], acc[3], 0, 0, 0);
  }
  // D layout: col = lane&15, row = (lane>>4)*4 + reg
  u16* out = zp + ((size_t)kc * BATCH + mt * 16) * RR;
#pragma unroll
  for (int t = 0; t < 4; ++t)
#pragma unroll
    for (int q = 0; q < 4; ++q)
      out[(g * 4 + q) * RR + t * 16 + l15] = f2bfu(acc[t][q]);
}

// ---- reduce 128 bf16 partials -> z bf16 [BATCH][RR] (unchanged) -----------
__global__ __launch_bounds__(1024) void k_red(const u16* __restrict__ zp,
                                              u16* __restrict__ zb) {
  __shared__ float part[4][256];
  int il = threadIdx.x & 255;
  int tg = threadIdx.x >> 8;
  int i = blockIdx.x * 256 + il;
  const u16* p = zp + (size_t)tg * 32 * (BATCH * RR) + i;
  float s0 = 0.f, s1 = 0.f, s2 = 0.f, s3 = 0.f;
#pragma unroll
  for (int t = 0; t < 32; t += 4) {
    s0 += bf2f(p[(size_t)(t + 0) * (BATCH * RR)]);
    s1 += bf2f(p[(size_t)(t + 1) * (BATCH * RR)]);
    s2 += bf2f(p[(size_t)(t + 2) * (BATCH * RR)]);
    s3 += bf2f(p[(size_t)(t + 3) * (BATCH * RR)]);
  }
  part[tg][il] = (s0 + s1) + (s2 + s3);
  __syncthreads();
  if (tg == 0)
    zb[i] = f2bfu((part[0][il] + part[1][il]) + (part[2][il] + part[3][il]));
}

// ---- GEMM2: y[b][n] = z[b][:] @ U[n][:]  (K = 64) -------------------------
// Identical to round 4 EXCEPT: plain stores (no nontemporal). Single-variable
// ablation: nt-store path suspected as the 1.5 TB/s device-wide write limit.
__global__ __launch_bounds__(256) void k2(const u16* __restrict__ zb,
                                          const float* __restrict__ U,
                                          float* __restrict__ y) {
  __shared__ float lds[16][260];
  int bid = blockIdx.x;
  int eff = (bid & 7) * 256 + (bid >> 3);  // bijective (2048 % 8 == 0)
  int bt = eff & 31;                       // 32 batch tiles of 16
  int nt = eff >> 5;                       // 64 n tiles of 512, XCD-contiguous
  int lane = threadIdx.x & 63;
  int w = threadIdx.x >> 6;
  int l15 = lane & 15, g = lane >> 4;
  int b0 = bt * 16;
  int n0 = nt * 512;
  const u16* A = zb + (b0 + l15) * RR + g * 8;
  bf16x8 a0 = *reinterpret_cast<const bf16x8*>(A);
  bf16x8 a1 = *reinterpret_cast<const bf16x8*>(A + 32);
  f32x4 acc[8] = {};
#pragma unroll
  for (int j = 0; j < 8; ++j) {
    const float* Bp = U + (size_t)(n0 + (w + 4 * j) * 16 + l15) * RR + g * 8;
    f32x4 u0 = *reinterpret_cast<const f32x4*>(Bp);
    f32x4 u1 = *reinterpret_cast<const f32x4*>(Bp + 4);
    acc[j] = __builtin_amdgcn_mfma_f32_16x16x32_bf16(a0, cvt8(u0, u1), acc[j], 0, 0, 0);
    f32x4 u2 = *reinterpret_cast<const f32x4*>(Bp + 32);
    f32x4 u3 = *reinterpret_cast<const f32x4*>(Bp + 36);
    acc[j] = __builtin_amdgcn_mfma_f32_16x16x32_bf16(a1, cvt8(u2, u3), acc[j], 0, 0, 0);
  }
#pragma unroll
  for (int p = 0; p < 2; ++p) {
    if (p) __syncthreads();  // protect LDS reuse across halves
#pragma unroll
    for (int i = 0; i < 4; ++i) {
      int j = 4 * p + i;
#pragma unroll
      for (int q = 0; q < 4; ++q)
        lds[g * 4 + q][w * 16 + 64 * i + l15] = acc[j][q];
    }
    __syncthreads();
#pragma unroll
    for (int rr = 0; rr < 4; ++rr) {
      int row = 4 * w + rr;
      f32x4 v = *reinterpret_cast<const f32x4*>(&lds[row][lane * 4]);
      *reinterpret_cast<f32x4*>(y + (size_t)(b0 + row) * NPOST + n0 + 256 * p + lane * 4) = v;
    }
  }
}

extern "C" void kernel_launch(void* const* d_in, const int* in_sizes, int n_in,
                              void* d_out, int out_size, void* d_ws, size_t ws_size,
                              hipStream_t stream) {
  const float* spikes = (const float*)d_in[0];
  const float* U = (const float*)d_in[1];
  const float* V = (const float*)d_in[2];
  // d_in[3..5]: CSR mask — dead in the reference, unused.
  float* y = (float*)d_out;
  char* ws = (char*)d_ws;
  u16* zp = (u16*)ws;                    // 8 MiB  [KSPLIT][BATCH][RR] bf16
  u16* zb = (u16*)(ws + (8u << 20));     // 64 KiB [BATCH][RR] bf16

  k1<<<1024, 256, 0, stream>>>(spikes, V, zp);
  k_red<<<128, 1024, 0, stream>>>(zp, zb);
  k2<<<2048, 256, 0, stream>>>(zb, U, y);
}

// Round 7
// 52.125 us; speedup vs baseline: 1.3674x; 1.3674x over previous
//
#include <hip/hip_runtime.h>

#define NPRE 32768
#define NPOST 32768
#define RR 64
#define BATCH 512
#define KSPLIT 128
#define KCHUNK 256  // NPRE / KSPLIT

typedef float f32x4 __attribute__((ext_vector_type(4)));
typedef __bf16 bf16x8 __attribute__((ext_vector_type(8)));
typedef unsigned short u16;
typedef unsigned int u32;

static __device__ __forceinline__ u16 f2bfu(float f) {
  u32 u = __builtin_bit_cast(u32, f);
  return (u16)((u + 0x7fffu + ((u >> 16) & 1u)) >> 16);  // RNE round to bf16
}
static __device__ __forceinline__ __bf16 u2bf(u16 s) {
  return __builtin_bit_cast(__bf16, s);
}
static __device__ __forceinline__ float bf2f(u16 s) {
  return __builtin_bit_cast(float, (u32)s << 16);
}
static __device__ __forceinline__ bf16x8 cvt8(f32x4 lo, f32x4 hi) {
  bf16x8 b;
  b[0] = u2bf(f2bfu(lo.x)); b[1] = u2bf(f2bfu(lo.y));
  b[2] = u2bf(f2bfu(lo.z)); b[3] = u2bf(f2bfu(lo.w));
  b[4] = u2bf(f2bfu(hi.x)); b[5] = u2bf(f2bfu(hi.y));
  b[6] = u2bf(f2bfu(hi.z)); b[7] = u2bf(f2bfu(hi.w));
  return b;
}

// ---- GEMM1 (frozen): zp[kc][b][r] = S[b][kslice] @ V[kslice][r] -----------
__global__ __launch_bounds__(256, 4) void k1(const float* __restrict__ S,
                                             const float* __restrict__ V,
                                             u16* __restrict__ zp) {
  int bid = blockIdx.x;
  int eff = (bid & 7) * 128 + (bid >> 3);  // bijective XCD swizzle (1024 % 8 == 0)
  int grp = eff & 7;
  int kc = eff >> 3;                       // XCD-contiguous kc range
  int lane = threadIdx.x & 63;
  int w = threadIdx.x >> 6;
  int mt = grp * 4 + w;                    // 0..31
  int l15 = lane & 15, g = lane >> 4;
  const float* A = S + (size_t)(mt * 16 + l15) * NPRE + kc * KCHUNK + g * 8;
  const float* Vb = V + (size_t)(kc * KCHUNK + g * 8) * RR + l15;
  f32x4 acc[4] = {};
#pragma unroll 2
  for (int ks = 0; ks < KCHUNK / 32; ++ks) {
    f32x4 a0 = __builtin_nontemporal_load(reinterpret_cast<const f32x4*>(A + ks * 32));
    f32x4 a1 = __builtin_nontemporal_load(reinterpret_cast<const f32x4*>(A + ks * 32 + 4));
    bf16x8 af = cvt8(a0, a1);
    const float* Vk = Vb + (size_t)ks * 32 * RR;
    bf16x8 bfr[4];
#pragma unroll
    for (int t = 0; t < 4; ++t)
#pragma unroll
      for (int j = 0; j < 8; ++j)
        bfr[t][j] = u2bf(f2bfu(Vk[j * RR + t * 16]));  // V[k][r], r = t*16+l15
    acc[0] = __builtin_amdgcn_mfma_f32_16x16x32_bf16(af, bfr[0], acc[0], 0, 0, 0);
    acc[1] = __builtin_amdgcn_mfma_f32_16x16x32_bf16(af, bfr[1], acc[1], 0, 0, 0);
    acc[2] = __builtin_amdgcn_mfma_f32_16x16x32_bf16(af, bfr[2], acc[2], 0, 0, 0);
    acc[3] = __builtin_amdgcn_mfma_f32_16x16x32_bf16(af, bfr[3], acc[3], 0, 0, 0);
  }
  // D layout: col = lane&15, row = (lane>>4)*4 + reg
  u16* out = zp + ((size_t)kc * BATCH + mt * 16) * RR;
#pragma unroll
  for (int t = 0; t < 4; ++t)
#pragma unroll
    for (int q = 0; q < 4; ++q)
      out[(g * 4 + q) * RR + t * 16 + l15] = f2bfu(acc[t][q]);
}

// ---- reduce 128 bf16 partials -> z bf16 [BATCH][RR] (frozen) --------------
__global__ __launch_bounds__(1024) void k_red(const u16* __restrict__ zp,
                                              u16* __restrict__ zb) {
  __shared__ float part[4][256];
  int il = threadIdx.x & 255;
  int tg = threadIdx.x >> 8;
  int i = blockIdx.x * 256 + il;
  const u16* p = zp + (size_t)tg * 32 * (BATCH * RR) + i;
  float s0 = 0.f, s1 = 0.f, s2 = 0.f, s3 = 0.f;
#pragma unroll
  for (int t = 0; t < 32; t += 4) {
    s0 += bf2f(p[(size_t)(t + 0) * (BATCH * RR)]);
    s1 += bf2f(p[(size_t)(t + 1) * (BATCH * RR)]);
    s2 += bf2f(p[(size_t)(t + 2) * (BATCH * RR)]);
    s3 += bf2f(p[(size_t)(t + 3) * (BATCH * RR)]);
  }
  part[tg][il] = (s0 + s1) + (s2 + s3);
  __syncthreads();
  if (tg == 0)
    zb[i] = f2bfu((part[0][il] + part[1][il]) + (part[2][il] + part[3][il]));
}

// ---- GEMM2 v3: y[b][n] = z @ U^T — streaming structure --------------------
// 512 blocks = (64 n-tiles of 512) x (8 b-groups of 64). Block stages its
// 512x64 U slice ONCE into LDS as bf16 (XOR-swizzled, conflict-free), then
// loops 4 b-tiles: zb frags -> 16 MFMA -> direct stores. Stores spread
// across the block lifetime; U global traffic 256->64 MB.
// 64 KB LDS -> 2 blocks/CU. XCD swizzle: same-slice blocks on same XCD.
__global__ __launch_bounds__(256) void k2(const u16* __restrict__ zb,
                                          const float* __restrict__ U,
                                          float* __restrict__ y) {
  __shared__ u16 Ub[512 * 64];  // 64 KB, swizzled: byte = (row*128+col*2)^((row&7)<<4)
  int bid = blockIdx.x;
  int eff = (bid & 7) * 64 + (bid >> 3);  // bijective (512 % 8 == 0)
  int nt = eff >> 3;                      // 8 consecutive n-tiles per XCD
  int bg = eff & 7;
  int n0 = nt * 512;
  int t = threadIdx.x;
  int lane = t & 63;
  int w = t >> 6;
  int l15 = lane & 15, g = lane >> 4;
  char* Uc = reinterpret_cast<char*>(Ub);

  // stage U slice -> LDS bf16: 512x64 = 32768 floats = 32 iters x 1024
#pragma unroll
  for (int i = 0; i < 32; ++i) {
    int f = i * 1024 + t * 4;  // linear float idx within 512x64 slice
    int row = f >> 6;
    int colb = (f & 63) * 2;   // byte col, 8B-aligned
    f32x4 u = *reinterpret_cast<const f32x4*>(U + (size_t)n0 * RR + f);
    uint2 pk;
    pk.x = (u32)f2bfu(u.x) | ((u32)f2bfu(u.y) << 16);
    pk.y = (u32)f2bfu(u.z) | ((u32)f2bfu(u.w) << 16);
    *reinterpret_cast<uint2*>(Uc + ((row * 128 + colb) ^ ((row & 7) << 4))) = pk;
  }
  __syncthreads();

#pragma unroll
  for (int it = 0; it < 4; ++it) {
    int b0 = bg * 64 + it * 16;
    const u16* A = zb + (size_t)(b0 + l15) * RR + g * 8;
    bf16x8 a0 = *reinterpret_cast<const bf16x8*>(A);
    bf16x8 a1 = *reinterpret_cast<const bf16x8*>(A + 32);
    f32x4 acc[8] = {};
#pragma unroll
    for (int j = 0; j < 8; ++j) {
      int row = (w + 4 * j) * 16 + l15;  // 0..511
      int base = row * 128;
      int swz = (row & 7) << 4;
      bf16x8 bA = *reinterpret_cast<const bf16x8*>(Uc + ((base + g * 16) ^ swz));
      bf16x8 bB = *reinterpret_cast<const bf16x8*>(Uc + ((base + 64 + g * 16) ^ swz));
      acc[j] = __builtin_amdgcn_mfma_f32_16x16x32_bf16(a0, bA, acc[j], 0, 0, 0);
      acc[j] = __builtin_amdgcn_mfma_f32_16x16x32_bf16(a1, bB, acc[j], 0, 0, 0);
    }
    // direct stores: D layout col=l15, row=g*4+q; 64B-contiguous per 16 lanes
    float* yb = y + (size_t)b0 * NPOST + n0;
#pragma unroll
    for (int j = 0; j < 8; ++j) {
      int tau = w + 4 * j;
#pragma unroll
      for (int q = 0; q < 4; ++q)
        yb[(size_t)(g * 4 + q) * NPOST + tau * 16 + l15] = acc[j][q];
    }
  }
}

extern "C" void kernel_launch(void* const* d_in, const int* in_sizes, int n_in,
                              void* d_out, int out_size, void* d_ws, size_t ws_size,
                              hipStream_t stream) {
  const float* spikes = (const float*)d_in[0];
  const float* U = (const float*)d_in[1];
  const float* V = (const float*)d_in[2];
  // d_in[3..5]: CSR mask — dead in the reference, unused.
  float* y = (float*)d_out;
  char* ws = (char*)d_ws;
  u16* zp = (u16*)ws;                    // 8 MiB  [KSPLIT][BATCH][RR] bf16
  u16* zb = (u16*)(ws + (8u << 20));     // 64 KiB [BATCH][RR] bf16

  k1<<<1024, 256, 0, stream>>>(spikes, V, zp);
  k_red<<<128, 1024, 0, stream>>>(zp, zb);
  k2<<<512, 256, 0, stream>>>(zb, U, y);
}